// Round 1
// baseline (314.239 us; speedup 1.0000x reference)
//
#include <hip/hip_runtime.h>

typedef __attribute__((ext_vector_type(8))) short short8;
typedef __attribute__((ext_vector_type(4))) float f32x4;

#define MFMA16(a,b,c) __builtin_amdgcn_mfma_f32_16x16x32_bf16(a,b,c,0,0,0)

__device__ __forceinline__ unsigned short f2bf(float f){
  unsigned int u = __float_as_uint(f);
  u += 0x7FFF + ((u>>16)&1);
  return (unsigned short)(u>>16);
}

__device__ __forceinline__ void gl_lds16(const void* g, void* l){
  __builtin_amdgcn_global_load_lds((const __attribute__((address_space(1))) void*)g,
                                   (__attribute__((address_space(3))) void*)l, 16, 0, 0);
}

__global__ void cvt_bf16(const float* __restrict__ src, unsigned short* __restrict__ dst, int n){
  int i = (blockIdx.x*blockDim.x + threadIdx.x)*4;
  if (i + 3 < n){
    float4 v = *(const float4*)(src + i);
    ushort4 o;
    o.x = f2bf(v.x); o.y = f2bf(v.y); o.z = f2bf(v.z); o.w = f2bf(v.w);
    *(ushort4*)(dst + i) = o;
  }
}

// C[m,n] = sum_k A[m,k]*Bw[n,k]  (Bw row-major [N,K] = W, i.e. y = x W^T)
// MODE 0: scatter to Q/K [B,H,S,HD] bf16 and VT [B,H,HD,S] bf16 with per-third bias
// MODE 1: f32 out row-major [M,N] with bias0
template<int MODE>
__global__ __launch_bounds__(256) void gemm_bt(
  const unsigned short* __restrict__ A,
  const unsigned short* __restrict__ Bw,
  const float* __restrict__ bias0, const float* __restrict__ bias1, const float* __restrict__ bias2,
  unsigned short* __restrict__ Qo, unsigned short* __restrict__ Ko, unsigned short* __restrict__ VTo,
  float* __restrict__ Co,
  int M, int N, int K)
{
  __shared__ unsigned short As[2][128*32];
  __shared__ unsigned short Bs[2][128*32];
  const int tid = threadIdx.x;
  const int m0 = blockIdx.y*128, n0 = blockIdx.x*128;
  const int w = tid>>6, lane = tid&63, lr = lane&15, lg = lane>>4;
  const int wm = w>>1, wn = w&1;
  const int nk = K/32;

  auto stage = [&](int buf, int kt){
    const unsigned short* Ag = A + (size_t)m0*K + kt*32;
    const unsigned short* Bg = Bw + (size_t)n0*K + kt*32;
    #pragma unroll
    for (int it=0; it<2; ++it){
      int slot = it*256 + tid;
      gl_lds16(Ag + (size_t)(slot>>2)*K + (slot&3)*8, &As[buf][slot*8]);
    }
    #pragma unroll
    for (int it=0; it<2; ++it){
      int slot = it*256 + tid;
      gl_lds16(Bg + (size_t)(slot>>2)*K + (slot&3)*8, &Bs[buf][slot*8]);
    }
  };

  f32x4 acc[4][4] = {};
  stage(0,0);
  for (int kt=0; kt<nk; ++kt){
    int cur = kt&1;
    __syncthreads();
    if (kt+1 < nk) stage(cur^1, kt+1);
    short8 af[4], bfr[4];
    #pragma unroll
    for (int i=0;i<4;++i) af[i]  = *(const short8*)&As[cur][(wm*64 + i*16 + lr)*32 + lg*8];
    #pragma unroll
    for (int j=0;j<4;++j) bfr[j] = *(const short8*)&Bs[cur][(wn*64 + j*16 + lr)*32 + lg*8];
    #pragma unroll
    for (int i=0;i<4;++i)
      #pragma unroll
      for (int j=0;j<4;++j)
        acc[i][j] = MFMA16(af[i], bfr[j], acc[i][j]);
  }

  #pragma unroll
  for (int i=0;i<4;++i){
    #pragma unroll
    for (int j=0;j<4;++j){
      const int n  = n0 + wn*64 + j*16 + lr;
      const int mb = m0 + wm*64 + i*16 + lg*4;
      if (MODE==0){
        const int which = n>>10, nn = n&1023;
        const float bv = (which==0) ? bias0[nn] : (which==1) ? bias1[nn] : bias2[nn];
        const int h = nn>>6, hd = nn&63;
        #pragma unroll
        for (int r=0;r<4;++r){
          const int m = mb + r;
          const int b = m>>11, s = m&2047;
          const unsigned short u = f2bf(acc[i][j][r] + bv);
          const size_t bh = (size_t)(b*16 + h);
          if (which==0)      Qo[(bh*2048 + s)*64 + hd] = u;
          else if (which==1) Ko[(bh*2048 + s)*64 + hd] = u;
          else               VTo[(bh*64 + hd)*2048 + s] = u;
        }
      } else {
        const float bv = bias0[n];
        #pragma unroll
        for (int r=0;r<4;++r){
          const int m = mb + r;
          Co[(size_t)m*N + n] = acc[i][j][r] + bv;
        }
      }
    }
  }
}

// Attention: grid(S/64, B*H), 256 thr. Wave w owns q rows [qt*64+w*16, +16).
// scores = QK^T/8 - lam*(|i-j|>102); online softmax over KV tiles of 32.
__global__ __launch_bounds__(256) void attn_k(
  const unsigned short* __restrict__ Qb,
  const unsigned short* __restrict__ Kb,
  const unsigned short* __restrict__ VT,
  const float* __restrict__ u_prev,
  unsigned short* __restrict__ Out)  // [B,S,H*HD] bf16
{
  const int qt = blockIdx.x, bh = blockIdx.y;
  const int b = bh>>4, h = bh&15;
  const float lam = 10.f * __expf(-5.f * u_prev[b]);
  const int w = threadIdx.x>>6, lane = threadIdx.x&63, lr = lane&15, lg = lane>>4;
  const int q0 = qt*64 + w*16;

  const unsigned short* Qp = Qb + (size_t)bh*2048*64;
  const unsigned short* Kp = Kb + (size_t)bh*2048*64;
  const unsigned short* Vp = VT + (size_t)bh*64*2048;

  __shared__ unsigned short p_lds[4][16][32];

  short8 qf[2];
  #pragma unroll
  for (int s=0;s<2;++s) qf[s] = *(const short8*)&Qp[(size_t)(q0+lr)*64 + s*32 + lg*8];

  float m_run[4], l_run[4];
  f32x4 o_acc[4] = {};
  #pragma unroll
  for (int r=0;r<4;++r){ m_run[r] = -1e30f; l_run[r] = 0.f; }

  for (int kt=0; kt<64; ++kt){
    const int k0 = kt*32;
    f32x4 sacc[2] = {};
    #pragma unroll
    for (int t=0;t<2;++t){
      short8 kf0 = *(const short8*)&Kp[(size_t)(k0 + t*16 + lr)*64 + 0 + lg*8];
      short8 kf1 = *(const short8*)&Kp[(size_t)(k0 + t*16 + lr)*64 + 32 + lg*8];
      sacc[t] = MFMA16(qf[0], kf0, sacc[t]);
      sacc[t] = MFMA16(qf[1], kf1, sacc[t]);
    }
    float sc[2][4], mx[4];
    #pragma unroll
    for (int r=0;r<4;++r){
      const int qi = q0 + lg*4 + r;
      #pragma unroll
      for (int t=0;t<2;++t){
        const int ki = k0 + t*16 + lr;
        float v = sacc[t][r]*0.125f;
        int dd = qi - ki; if (dd<0) dd = -dd;
        if (dd > 102) v -= lam;
        sc[t][r] = v;
      }
      mx[r] = fmaxf(sc[0][r], sc[1][r]);
    }
    #pragma unroll
    for (int off=1; off<16; off<<=1)
      #pragma unroll
      for (int r=0;r<4;++r)
        mx[r] = fmaxf(mx[r], __shfl_xor(mx[r], off, 64));

    float p[2][4];
    #pragma unroll
    for (int r=0;r<4;++r){
      const float mnew = fmaxf(m_run[r], mx[r]);
      const float scale = __expf(m_run[r] - mnew);
      m_run[r] = mnew;
      float ls = 0.f;
      #pragma unroll
      for (int t=0;t<2;++t){ p[t][r] = __expf(sc[t][r] - mnew); ls += p[t][r]; }
      l_run[r] = l_run[r]*scale + ls;
      #pragma unroll
      for (int dt=0;dt<4;++dt) o_acc[dt][r] *= scale;
    }
    #pragma unroll
    for (int t=0;t<2;++t)
      #pragma unroll
      for (int r=0;r<4;++r)
        p_lds[w][lg*4+r][t*16+lr] = f2bf(p[t][r]);

    short8 pa = *(const short8*)&p_lds[w][lr][lg*8];
    #pragma unroll
    for (int dt=0;dt<4;++dt){
      short8 vf = *(const short8*)&Vp[(size_t)(dt*16+lr)*2048 + k0 + lg*8];
      o_acc[dt] = MFMA16(pa, vf, o_acc[dt]);
    }
  }
  #pragma unroll
  for (int off=1; off<16; off<<=1)
    #pragma unroll
    for (int r=0;r<4;++r)
      l_run[r] += __shfl_xor(l_run[r], off, 64);

  #pragma unroll
  for (int dt=0;dt<4;++dt){
    #pragma unroll
    for (int r=0;r<4;++r){
      const int qi = q0 + lg*4 + r;
      const float val = o_acc[dt][r] / l_run[r];
      Out[((size_t)b*2048 + qi)*1024 + h*64 + dt*16 + lr] = f2bf(val);
    }
  }
}

__global__ void tail_k(const float* __restrict__ u, float* __restrict__ out){
  int i = threadIdx.x;
  if (i < 2) out[4194304 + i] = 10.f*__expf(-5.f*u[i]);
}

extern "C" void kernel_launch(void* const* d_in, const int* in_sizes, int n_in,
                              void* d_out, int out_size, void* d_ws, size_t ws_size,
                              hipStream_t stream){
  const float* x  = (const float*)d_in[0];
  const float* u  = (const float*)d_in[1];
  const float* Wq = (const float*)d_in[2];
  const float* bq = (const float*)d_in[3];
  const float* Wk = (const float*)d_in[4];
  const float* bk = (const float*)d_in[5];
  const float* Wv = (const float*)d_in[6];
  const float* bv = (const float*)d_in[7];
  const float* Wo = (const float*)d_in[8];
  const float* bo = (const float*)d_in[9];
  float* out = (float*)d_out;

  unsigned char* ws = (unsigned char*)d_ws;
  unsigned short* xb    = (unsigned short*)(ws);              // 4096x1024 bf16 (8MB)
  unsigned short* attnb = xb;                                 // reused after GEMM1
  unsigned short* Wqkvb = (unsigned short*)(ws + 8388608);    // 3072x1024 (6MB)
  unsigned short* Wob   = (unsigned short*)(ws + 14680064);   // 1024x1024 (2MB)
  unsigned short* Qb2   = (unsigned short*)(ws + 16777216);   // [B,H,S,HD] (8MB)
  unsigned short* Kb2   = (unsigned short*)(ws + 25165824);   // [B,H,S,HD] (8MB)
  unsigned short* VTb   = (unsigned short*)(ws + 33554432);   // [B,H,HD,S] (8MB)

  cvt_bf16<<<4096, 256, 0, stream>>>(x,  xb, 4194304);
  cvt_bf16<<<1024, 256, 0, stream>>>(Wq, Wqkvb,            1048576);
  cvt_bf16<<<1024, 256, 0, stream>>>(Wk, Wqkvb + 1048576,  1048576);
  cvt_bf16<<<1024, 256, 0, stream>>>(Wv, Wqkvb + 2097152,  1048576);
  cvt_bf16<<<1024, 256, 0, stream>>>(Wo, Wob, 1048576);

  gemm_bt<0><<<dim3(24,32), 256, 0, stream>>>(xb, Wqkvb, bq, bk, bv,
                                              Qb2, Kb2, VTb, nullptr, 4096, 3072, 1024);
  attn_k<<<dim3(32,32), 256, 0, stream>>>(Qb2, Kb2, VTb, u, attnb);
  gemm_bt<1><<<dim3(8,32), 256, 0, stream>>>(attnb, Wob, bo, nullptr, nullptr,
                                             nullptr, nullptr, nullptr, out, 4096, 1024, 1024);
  tail_k<<<1, 64, 0, stream>>>(u, out);
}